// Round 4
// baseline (356.000 us; speedup 1.0000x reference)
//
#include <hip/hip_runtime.h>
#include <hip/hip_bf16.h>

#define D 128            // D_IN == D_OUT == 128
#define GRID_BLOCKS 512  // 2 blocks/CU on 256 CUs -- co-resident by construction

typedef __attribute__((ext_vector_type(8))) short bf16x8;  // 8 bf16 = 4 VGPRs
typedef __attribute__((ext_vector_type(4))) float f32x4;

static __device__ __forceinline__ ushort f2bf(float f) {
    __hip_bfloat16 h = __float2bfloat16(f);  // RNE
    return *(ushort*)&h;
}
static __device__ __forceinline__ float bfl(uint u) { return __uint_as_float(u << 16); }
static __device__ __forceinline__ float bfh(uint u) { return __uint_as_float(u & 0xffff0000u); }

// ---------------- fused GCN: [W-stage + GEMM tiles] -> grid barrier -> SpMM ----------------
// Ablation experiment: total has been spmm + C with C = 109.5 +/- 1 us across 4
// rounds, insensitive to gemm changes; gemm roofline arithmetic says ~15 us.
// This kernel removes every inter-dispatch cost that is under our control:
// swizzle_w dispatch, Wz global round-trip, and 2 kernel-boundary gaps.
// GEMM math and spmm v5 inner loop are verbatim -> numerics unchanged.
__global__ __launch_bounds__(256, 2) void gcn_fused(const float* __restrict__ X,
                                                    const float* __restrict__ W,
                                                    const float* __restrict__ deg,
                                                    const int* __restrict__ rp,
                                                    const int* __restrict__ ci,
                                                    ushort* __restrict__ Xp,
                                                    uint* __restrict__ bar,
                                                    float* __restrict__ out, int n)
{
    __shared__ ushort wsh[32 * 64 * 8];   // 32 KB fragment-order W copy
    const int tid  = threadIdx.x;
    const int lane = tid & 63;
    const int wave = tid >> 6;

    // ---- phase A0: build wsh directly from fp32 W (64 KB, L2-resident) ----
    // slot s = (combo = wave + i*4, lane); 8 strided dword reads per slot.
    // Same f2bf RNE as the old swizzle_w -> bitwise-identical fragments.
    #pragma unroll
    for (int i = 0; i < 8; ++i) {
        const int s     = tid + i * 256;        // 0..2047
        const int combo = s >> 6;               // ks*8+nb
        const int ks = combo >> 3, nb = combo & 7;
        const int krow = ks * 32 + ((lane >> 4) << 3);
        const int col  = nb * 16 + (lane & 15);
        ushort u[8];
        #pragma unroll
        for (int j = 0; j < 8; ++j) u[j] = f2bf(W[(krow + j) * D + col]);
        uint4 p;
        p.x = (uint)u[0] | ((uint)u[1] << 16);
        p.y = (uint)u[2] | ((uint)u[3] << 16);
        p.z = (uint)u[4] | ((uint)u[5] << 16);
        p.w = (uint)u[6] | ((uint)u[7] << 16);
        ((uint4*)wsh)[s] = p;
    }
    __syncthreads();

    // ---- phase A1: GEMM tiles, grid-stride (verbatim v3 swapped-operand body) ----
    const int m = lane & 15, quad = lane >> 4;
    const int ntiles = (n + 127) >> 7;

    for (int tile = blockIdx.x; tile < ntiles; tile += GRID_BLOCKS) {
        const int r0 = tile * 128 + wave * 32;

        bf16x8 xfrag[2][4];
        #pragma unroll
        for (int t = 0; t < 2; ++t) {
            long long arow = r0 + t * 16 + m;
            if (arow >= n) arow = n - 1;           // clamp loads; stores guarded
            const float* xa = X + arow * D + quad * 8;
            #pragma unroll
            for (int ks = 0; ks < 4; ++ks) {
                float4 lo = *(const float4*)(xa + ks * 32);
                float4 hi = *(const float4*)(xa + ks * 32 + 4);
                bf16x8 a;
                a[0] = (short)f2bf(lo.x); a[1] = (short)f2bf(lo.y);
                a[2] = (short)f2bf(lo.z); a[3] = (short)f2bf(lo.w);
                a[4] = (short)f2bf(hi.x); a[5] = (short)f2bf(hi.y);
                a[6] = (short)f2bf(hi.z); a[7] = (short)f2bf(hi.w);
                xfrag[t][ks] = a;
            }
        }

        f32x4 acc[2][8];
        #pragma unroll
        for (int t = 0; t < 2; ++t)
            #pragma unroll
            for (int nb = 0; nb < 8; ++nb) acc[t][nb] = (f32x4){0.f, 0.f, 0.f, 0.f};

        #pragma unroll
        for (int nb = 0; nb < 8; ++nb) {
            #pragma unroll
            for (int ks = 0; ks < 4; ++ks) {
                bf16x8 w = *(const bf16x8*)(wsh + ((size_t)((ks * 8 + nb) * 64 + lane)) * 8);
                // swapped operands: D = (W^T tile)*(X^T tile) = (X*W)^T tile
                acc[0][nb] = __builtin_amdgcn_mfma_f32_16x16x32_bf16(w, xfrag[0][ks], acc[0][nb], 0, 0, 0);
                acc[1][nb] = __builtin_amdgcn_mfma_f32_16x16x32_bf16(w, xfrag[1][ks], acc[1][nb], 0, 0, 0);
            }
        }

        #pragma unroll
        for (int t = 0; t < 2; ++t) {
            const int row = r0 + t * 16 + m;
            if (row < n) {
                const float dr = deg[row];
                ushort* dstrow = Xp + (size_t)row * D + quad * 4;
                #pragma unroll
                for (int nb = 0; nb < 8; ++nb) {
                    uint2 p;
                    p.x = (uint)f2bf(dr * acc[t][nb][0]) | ((uint)f2bf(dr * acc[t][nb][1]) << 16);
                    p.y = (uint)f2bf(dr * acc[t][nb][2]) | ((uint)f2bf(dr * acc[t][nb][3]) << 16);
                    *(uint2*)(dstrow + nb * 16) = p;
                }
            }
        }
    }

    // ---- grid barrier (single-use; bar zeroed by captured hipMemsetAsync) ----
    // Guide-endorsed cross-XCD mitigation: device-scope fence + device-scope
    // atomics. Co-residency guaranteed: 512 blocks, 2/CU by launch_bounds+LDS.
    __syncthreads();
    if (tid == 0) {
        __threadfence();   // flush this block's Xp stores device-wide (release)
        __hip_atomic_fetch_add(bar, 1u, __ATOMIC_ACQ_REL, __HIP_MEMORY_SCOPE_AGENT);
        while (__hip_atomic_load(bar, __ATOMIC_ACQUIRE, __HIP_MEMORY_SCOPE_AGENT) < (uint)GRID_BLOCKS)
            __builtin_amdgcn_s_sleep(2);
    }
    __syncthreads();
    // per-wave acquire so every wave's subsequent loads see all Xp writes
    (void)__hip_atomic_load(bar, __ATOMIC_ACQUIRE, __HIP_MEMORY_SCOPE_AGENT);

    // ---- phase B: SpMM, grid-stride (verbatim v5 wave-per-row body) ----
    const uint* __restrict__ Xq = (const uint*)Xp;   // one bf16 row = 64 uints
    const int ng = (n + 3) >> 2;                      // row-groups of 4 (1/wave)

    for (int g = blockIdx.x; g < ng; g += GRID_BLOCKS) {
        const int row = __builtin_amdgcn_readfirstlane(g * 4 + wave);
        if (row >= n) continue;                       // uniform
        const int beg = rp[row], end = rp[row + 1];   // uniform -> s_load

        float a0 = 0.f, a1 = 0.f, b0 = 0.f, b1 = 0.f;

        int e = beg;
        for (; e + 8 <= end; e += 8) {
            const int c0 = ci[e + 0], c1 = ci[e + 1], c2 = ci[e + 2], c3 = ci[e + 3];
            const int c4 = ci[e + 4], c5 = ci[e + 5], c6 = ci[e + 6], c7 = ci[e + 7];
            const uint v0 = Xq[(size_t)c0 * 64 + lane];
            const uint v1 = Xq[(size_t)c1 * 64 + lane];
            const uint v2 = Xq[(size_t)c2 * 64 + lane];
            const uint v3 = Xq[(size_t)c3 * 64 + lane];
            const uint v4 = Xq[(size_t)c4 * 64 + lane];
            const uint v5 = Xq[(size_t)c5 * 64 + lane];
            const uint v6 = Xq[(size_t)c6 * 64 + lane];
            const uint v7 = Xq[(size_t)c7 * 64 + lane];
            a0 += bfl(v0); a1 += bfh(v0);
            b0 += bfl(v1); b1 += bfh(v1);
            a0 += bfl(v2); a1 += bfh(v2);
            b0 += bfl(v3); b1 += bfh(v3);
            a0 += bfl(v4); a1 += bfh(v4);
            b0 += bfl(v5); b1 += bfh(v5);
            a0 += bfl(v6); a1 += bfh(v6);
            b0 += bfl(v7); b1 += bfh(v7);
        }

        if (e < end) {                     // clamped tail batch, still 8-deep
            int cc[8];
            #pragma unroll
            for (int j = 0; j < 8; ++j) {
                const int ee = e + j;
                cc[j] = ci[ee < end ? ee : end - 1];
            }
            uint vv[8];
            #pragma unroll
            for (int j = 0; j < 8; ++j) vv[j] = Xq[(size_t)cc[j] * 64 + lane];
            #pragma unroll
            for (int j = 0; j < 8; ++j) {
                if (e + j < end) { a0 += bfl(vv[j]); a1 += bfh(vv[j]); }
            }
        }

        const float dr = deg[row];         // uniform -> s_load
        float2 o;
        o.x = dr * (a0 + b0);
        o.y = dr * (a1 + b1);
        *(float2*)(out + (size_t)row * D + lane * 2) = o;
    }
}

extern "C" void kernel_launch(void* const* d_in, const int* in_sizes, int n_in,
                              void* d_out, int out_size, void* d_ws, size_t ws_size,
                              hipStream_t stream)
{
    const float* X   = (const float*)d_in[0];   // [N,128] fp32
    const float* W   = (const float*)d_in[1];   // [128,128] fp32
    const float* deg = (const float*)d_in[2];   // [N] fp32
    const int*   rp  = (const int*)d_in[3];     // [N+1] int32
    const int*   ci  = (const int*)d_in[4];     // [E] int32
    float* out = (float*)d_out;                 // [N,128] fp32
    const int n = in_sizes[2];                  // N = 100000

    ushort* Xp = (ushort*)d_ws;                 // X'' bf16: n*128*2 = 25.6 MB
    uint*  bar = (uint*)(Xp + (size_t)n * D);   // 4-byte barrier counter

    hipMemsetAsync(bar, 0, sizeof(uint), stream);   // capturable async node
    gcn_fused<<<GRID_BLOCKS, 256, 0, stream>>>(X, W, deg, rp, ci, Xp, bar, out, n);
}

// Round 5
// 180.040 us; speedup vs baseline: 1.9773x; 1.9773x over previous
//
#include <hip/hip_runtime.h>
#include <hip/hip_bf16.h>

#define D 128  // D_IN == D_OUT == 128

typedef __attribute__((ext_vector_type(8))) short bf16x8;  // 8 bf16 = 4 VGPRs
typedef __attribute__((ext_vector_type(4))) float f32x4;

static __device__ __forceinline__ ushort f2bf(float f) {
    __hip_bfloat16 h = __float2bfloat16(f);  // RNE
    return *(ushort*)&h;
}
static __device__ __forceinline__ float bfl(uint u) { return __uint_as_float(u << 16); }
static __device__ __forceinline__ float bfh(uint u) { return __uint_as_float(u & 0xffff0000u); }

// ---------------- GEMM v4: self-staging W + swapped-operand MFMA ----------------
// swizzle_w folded in: each block builds the 32 KB fragment-order W copy in LDS
// directly from fp32 W (64 KB, L2/L3-resident after the first block). This
// staging ran bitwise-correct inside round-4's fused kernel. Removes one
// dispatch + inter-kernel gap + the Wz global round-trip.
// MFMA operands swapped (W-frag as A, X-frag as B): D = (X·W)^T per tile, so
// each lane holds row r0+t*16+m, four consecutive cols nb*16+quad*4+{0..3}
// -> uint2 packed epilogue stores (8 B, coalesced).
__global__ __launch_bounds__(256) void gemm_mfma(const float* __restrict__ X,
                                                 const float* __restrict__ W,
                                                 const float* __restrict__ deg,
                                                 ushort* __restrict__ Xp, int n)
{
    __shared__ ushort wsh[32 * 64 * 8];   // 32 KB fragment-order W copy
    const int tid  = threadIdx.x;
    const int lane = tid & 63;
    const int wave = tid >> 6;

    // stage: slot s = tid + i*256 (s&63 == lane); same f2bf RNE as old swizzle_w
    #pragma unroll
    for (int i = 0; i < 8; ++i) {
        const int s     = tid + i * 256;        // 0..2047
        const int combo = s >> 6;               // ks*8+nb
        const int ks = combo >> 3, nb = combo & 7;
        const int krow = ks * 32 + ((lane >> 4) << 3);
        const int col  = nb * 16 + (lane & 15);
        ushort u[8];
        #pragma unroll
        for (int j = 0; j < 8; ++j) u[j] = f2bf(W[(krow + j) * D + col]);
        uint4 p;
        p.x = (uint)u[0] | ((uint)u[1] << 16);
        p.y = (uint)u[2] | ((uint)u[3] << 16);
        p.z = (uint)u[4] | ((uint)u[5] << 16);
        p.w = (uint)u[6] | ((uint)u[7] << 16);
        ((uint4*)wsh)[s] = p;
    }
    __syncthreads();

    const int m = lane & 15, quad = lane >> 4;
    const int r0 = blockIdx.x * 128 + wave * 32;   // 2 tiles: rows r0..+15, +16..+31

    // X-frags: lane holds X[r0+t*16+m][ks*32 + quad*8 .. +7] as bf16x8
    bf16x8 xfrag[2][4];
    #pragma unroll
    for (int t = 0; t < 2; ++t) {
        long long arow = r0 + t * 16 + m;
        if (arow >= n) arow = n - 1;               // clamp loads; stores guarded
        const float* xa = X + arow * D + quad * 8;
        #pragma unroll
        for (int ks = 0; ks < 4; ++ks) {
            float4 lo = *(const float4*)(xa + ks * 32);
            float4 hi = *(const float4*)(xa + ks * 32 + 4);
            bf16x8 a;
            a[0] = (short)f2bf(lo.x); a[1] = (short)f2bf(lo.y);
            a[2] = (short)f2bf(lo.z); a[3] = (short)f2bf(lo.w);
            a[4] = (short)f2bf(hi.x); a[5] = (short)f2bf(hi.y);
            a[6] = (short)f2bf(hi.z); a[7] = (short)f2bf(hi.w);
            xfrag[t][ks] = a;
        }
    }

    f32x4 acc[2][8];
    #pragma unroll
    for (int t = 0; t < 2; ++t)
        #pragma unroll
        for (int nb = 0; nb < 8; ++nb) acc[t][nb] = (f32x4){0.f, 0.f, 0.f, 0.f};

    #pragma unroll
    for (int nb = 0; nb < 8; ++nb) {
        #pragma unroll
        for (int ks = 0; ks < 4; ++ks) {
            bf16x8 w = *(const bf16x8*)(wsh + ((size_t)((ks * 8 + nb) * 64 + lane)) * 8);
            // swapped operands: D = (W^T tile)·(X^T tile) = (X·W)^T tile
            acc[0][nb] = __builtin_amdgcn_mfma_f32_16x16x32_bf16(w, xfrag[0][ks], acc[0][nb], 0, 0, 0);
            acc[1][nb] = __builtin_amdgcn_mfma_f32_16x16x32_bf16(w, xfrag[1][ks], acc[1][nb], 0, 0, 0);
        }
    }

    // epilogue: lane holds Xp[row = r0+t*16+m][cols nb*16+quad*4+{0..3}]
    #pragma unroll
    for (int t = 0; t < 2; ++t) {
        const int row = r0 + t * 16 + m;
        if (row < n) {
            const float dr = deg[row];
            ushort* dstrow = Xp + (size_t)row * D + quad * 4;
            #pragma unroll
            for (int nb = 0; nb < 8; ++nb) {
                uint2 p;
                p.x = (uint)f2bf(dr * acc[t][nb][0]) | ((uint)f2bf(dr * acc[t][nb][1]) << 16);
                p.y = (uint)f2bf(dr * acc[t][nb][2]) | ((uint)f2bf(dr * acc[t][nb][3]) << 16);
                *(uint2*)(dstrow + nb * 16) = p;
            }
        }
    }
}

// ---------------- SpMM v7: wave-per-row v5 body, 4 rows per wave ----------------
// v5's occupancy sat at ~59% with 16 VGPR and 0 LDS -> wave slots are not
// resource-limited; suspect block dispatch/drain churn at 25000 four-wave
// micro-blocks (~0.7 us lifetime). Outer loop gives each wave 4 CONSECUTIVE
// rows (contiguous ci ranges, amortized startup) with the v5 inner body kept
// verbatim per row -- NOT v6's mid-batch flush machinery (that regressed).
#define ROWS_PER_WAVE 4

__global__ __launch_bounds__(256) void spmm_csr(const ushort* __restrict__ Xp,
                                                const float* __restrict__ deg,
                                                const int* __restrict__ rp,
                                                const int* __restrict__ ci,
                                                float* __restrict__ out, int n)
{
    const int wid  = blockIdx.x * 4 + (threadIdx.x >> 6);   // wave id
    const int lane = threadIdx.x & 63;
    const uint* __restrict__ Xq = (const uint*)Xp;          // one bf16 row = 64 uints

    #pragma unroll 1
    for (int rr = 0; rr < ROWS_PER_WAVE; ++rr) {
        const int row = __builtin_amdgcn_readfirstlane(wid * ROWS_PER_WAVE + rr);
        if (row >= n) break;                    // uniform
        const int beg = rp[row], end = rp[row + 1];   // uniform -> s_load

        float a0 = 0.f, a1 = 0.f, b0 = 0.f, b1 = 0.f;

        int e = beg;
        for (; e + 8 <= end; e += 8) {
            const int c0 = ci[e + 0], c1 = ci[e + 1], c2 = ci[e + 2], c3 = ci[e + 3];
            const int c4 = ci[e + 4], c5 = ci[e + 5], c6 = ci[e + 6], c7 = ci[e + 7];
            const uint v0 = Xq[(size_t)c0 * 64 + lane];
            const uint v1 = Xq[(size_t)c1 * 64 + lane];
            const uint v2 = Xq[(size_t)c2 * 64 + lane];
            const uint v3 = Xq[(size_t)c3 * 64 + lane];
            const uint v4 = Xq[(size_t)c4 * 64 + lane];
            const uint v5 = Xq[(size_t)c5 * 64 + lane];
            const uint v6 = Xq[(size_t)c6 * 64 + lane];
            const uint v7 = Xq[(size_t)c7 * 64 + lane];
            a0 += bfl(v0); a1 += bfh(v0);
            b0 += bfl(v1); b1 += bfh(v1);
            a0 += bfl(v2); a1 += bfh(v2);
            b0 += bfl(v3); b1 += bfh(v3);
            a0 += bfl(v4); a1 += bfh(v4);
            b0 += bfl(v5); b1 += bfh(v5);
            a0 += bfl(v6); a1 += bfh(v6);
            b0 += bfl(v7); b1 += bfh(v7);
        }

        if (e < end) {                          // clamped tail batch, still 8-deep
            int cc[8];
            #pragma unroll
            for (int j = 0; j < 8; ++j) {
                const int ee = e + j;
                cc[j] = ci[ee < end ? ee : end - 1];
            }
            uint vv[8];
            #pragma unroll
            for (int j = 0; j < 8; ++j) vv[j] = Xq[(size_t)cc[j] * 64 + lane];
            #pragma unroll
            for (int j = 0; j < 8; ++j) {
                if (e + j < end) { a0 += bfl(vv[j]); a1 += bfh(vv[j]); }
            }
        }

        const float dr = deg[row];              // uniform -> s_load
        float2 o;
        o.x = dr * (a0 + b0);
        o.y = dr * (a1 + b1);
        *(float2*)(out + (size_t)row * D + lane * 2) = o;   // coalesced
    }
}

extern "C" void kernel_launch(void* const* d_in, const int* in_sizes, int n_in,
                              void* d_out, int out_size, void* d_ws, size_t ws_size,
                              hipStream_t stream)
{
    const float* X   = (const float*)d_in[0];   // [N,128] fp32
    const float* W   = (const float*)d_in[1];   // [128,128] fp32
    const float* deg = (const float*)d_in[2];   // [N] fp32
    const int*   rp  = (const int*)d_in[3];     // [N+1] int32
    const int*   ci  = (const int*)d_in[4];     // [E] int32
    float* out = (float*)d_out;                 // [N,128] fp32
    const int n = in_sizes[2];                  // N = 100000

    ushort* Xp = (ushort*)d_ws;                 // X'' bf16: n*128*2 = 25.6 MB

    const int rows_per_block = 4 * ROWS_PER_WAVE;               // 16
    const int spmm_blocks = (n + rows_per_block - 1) / rows_per_block;

    gemm_mfma<<<(n + 127) / 128, 256, 0, stream>>>(X, W, deg, Xp, n);
    spmm_csr<<<spmm_blocks, 256, 0, stream>>>(Xp, deg, rp, ci, out, n);
}